// Round 13
// baseline (1264.495 us; speedup 1.0000x reference)
//
#include <hip/hip_runtime.h>
#include <hip/hip_cooperative_groups.h>
#include <math.h>

namespace cg = cooperative_groups;

#define N_NODES 20000
#define NUM_EDGE 4096
#define DIM 256
#define KF 8
#define EOUT (KF + NUM_EDGE)   /* 4104 */
#define SEL 6001               /* floor(0.3*N)=6000 -> rank<=6000 -> 6001 nodes selected */
#define NBLK 512               /* cooperative grid; 511 streamer blocks + block 0 */
#define TOTW (NBLK * 4)        /* 2048 waves in the keys stage */
#define RPW 10                 /* rows per streamer wave: 511*4*10 = 20440 >= 20000 */

__device__ __forceinline__ unsigned fkey(float s) {
    unsigned u = __float_as_uint(s);
    return (u & 0x80000000u) ? ~u : (u | 0x80000000u);
}

__device__ __forceinline__ double wred(double v) {
#pragma unroll
    for (int m = 32; m > 0; m >>= 1) v += __shfl_xor(v, m);
    return v;
}

__global__ __launch_bounds__(256) void kFused(
    const float* __restrict__ H, const float* __restrict__ hidden,
    const float* __restrict__ int_emb, float* __restrict__ out,
    unsigned* __restrict__ keys, unsigned* __restrict__ mask32,
    unsigned long long* __restrict__ accum64) {
    __shared__ float    en_s[KF * DIM];    // 8 KB
    __shared__ unsigned lacc[NUM_EDGE];    // 16 KB
    __shared__ unsigned hist8[KF * 256];   // 8 KB (8-factor radix histograms)
    __shared__ int      eqlist_s[KF * 64]; // 2 KB
    __shared__ unsigned s_int[KF];
    __shared__ unsigned eqcnt[KF];
    __shared__ int      eqn_s[KF];

    int tid = threadIdx.x, lane = tid & 63, w = tid >> 6, bid = blockIdx.x;
    cg::grid_group grid = cg::this_grid();

    // ---- Stage 0: en into LDS (every block; bit-identical redundant compute) ----
    for (int f = w; f < KF; f += 4) {
        float4 e = ((const float4*)(int_emb + f * DIM))[lane];
        double ss = (double)e.x * e.x + (double)e.y * e.y + (double)e.z * e.z + (double)e.w * e.w;
        ss = wred(ss);
        float den = fmaxf((float)sqrt(ss), 1e-8f);
        float4 o;
        o.x = e.x / den; o.y = e.y / den; o.z = e.z / den; o.w = e.w / den;
        ((float4*)(en_s + f * DIM))[lane] = o;
    }
    __syncthreads();

    // ---- Stage 1: keys (all 2048 waves; same per-factor reduction tree as validated k1) ----
    for (int n = bid * 4 + w; n < N_NODES; n += TOTW) {
        float4 h = ((const float4*)(hidden + (size_t)n * DIM))[lane];
        double ss = (double)h.x * h.x + (double)h.y * h.y + (double)h.z * h.z + (double)h.w * h.w;
        ss = wred(ss);
        float den = fmaxf((float)sqrt(ss), 1e-8f);
        float hn0 = h.x / den, hn1 = h.y / den, hn2 = h.z / den, hn3 = h.w / den;
        double d[KF];
#pragma unroll
        for (int f = 0; f < KF; ++f) {
            float4 e = ((const float4*)(en_s + f * DIM))[lane];
            d[f] = (double)hn0 * e.x + (double)hn1 * e.y + (double)hn2 * e.z + (double)hn3 * e.w;
        }
#pragma unroll
        for (int st = 32; st > 0; st >>= 1) {
#pragma unroll
            for (int f = 0; f < KF; ++f) d[f] += __shfl_xor(d[f], st);
        }
        if (lane < KF) keys[(size_t)lane * N_NODES + n] = fkey((float)(10.0 * d[lane]));
    }

    grid.sync();   // keys published

    unsigned blo[RPW], bhi[RPW], rs[RPW];

    if (bid == 0) {
        // ---- Stage 2a (block 0): zero accumulator with device atomics (replay-safe) ----
        unsigned* a32 = (unsigned*)accum64;
        for (int i = tid; i < 2 * EOUT; i += 256) atomicExch(&a32[i], 0u);

        // ---- Stage 2b: 8-factor radix select (4 passes over L2-resident keys) ----
        unsigned prefix[KF]; int kk[KF];
#pragma unroll
        for (int f = 0; f < KF; ++f) { prefix[f] = 0u; kk[f] = SEL; }
        unsigned pmask = 0u;
        for (int shift = 24; shift >= 0; shift -= 8) {
            for (int i = tid; i < KF * 256; i += 256) hist8[i] = 0u;
            __syncthreads();
            for (int i = tid; i < N_NODES; i += 256) {
#pragma unroll
                for (int f = 0; f < KF; ++f) {
                    unsigned key = keys[(size_t)f * N_NODES + i];
                    if ((key & pmask) == prefix[f])
                        atomicAdd(&hist8[f * 256 + ((key >> shift) & 255u)], 1u);
                }
            }
            __syncthreads();
#pragma unroll
            for (int f = 0; f < KF; ++f) {        // identical scan in every thread
                int acc = 0; unsigned chosen = 0u;
                for (int b = 255; b >= 0; --b) {
                    int c = (int)hist8[f * 256 + b];
                    if (acc + c >= kk[f]) { chosen = (unsigned)b; kk[f] -= acc; break; }
                    acc += c;
                }
                prefix[f] |= chosen << shift;
            }
            pmask |= 255u << shift;
            __syncthreads();
        }
        // tie lists
        if (tid < KF) eqcnt[tid] = 0u;
        __syncthreads();
        for (int i = tid; i < N_NODES; i += 256) {
#pragma unroll
            for (int f = 0; f < KF; ++f) {
                if (keys[(size_t)f * N_NODES + i] == prefix[f]) {
                    unsigned p = atomicAdd(&eqcnt[f], 1u);
                    if (p < 64u) eqlist_s[f * 64 + p] = i;
                }
            }
        }
        __syncthreads();
        if (tid < KF) {
            int f = tid;
            int ne = eqcnt[f] < 64u ? (int)eqcnt[f] : 64;
            for (int a = 1; a < ne; ++a) {         // ascending insertion sort (stable rank)
                int v = eqlist_s[f * 64 + a]; int b = a - 1;
                while (b >= 0 && eqlist_s[f * 64 + b] > v) { eqlist_s[f * 64 + b + 1] = eqlist_s[f * 64 + b]; --b; }
                eqlist_s[f * 64 + b + 1] = v;
            }
            eqn_s[f] = ne;
        }
        __syncthreads();
        // ---- Stage 2c: masks for all nodes ----
        for (int g = tid; g < N_NODES; g += 256) {
            unsigned m = 0u;
#pragma unroll
            for (int f = 0; f < KF; ++f) {
                unsigned key = keys[(size_t)f * N_NODES + g];
                unsigned t = prefix[f];
                bool sel = key > t;
                if (key == t) {
                    int ne = eqn_s[f], nd = kk[f], pos = -1;
                    for (int i = 0; i < ne; ++i) if (eqlist_s[f * 64 + i] == g) { pos = i; break; }
                    sel = (pos >= 0 && pos < nd);
                }
                m |= (sel ? 1u : 0u) << f;
            }
            mask32[g] = m;
        }
    } else {
        // ---- Stage 2 (streamers): mask-free Phase A (validated round-10 logic) ----
        for (int i = tid; i < NUM_EDGE; i += 256) lacc[i] = 0u;
        if (tid < KF) s_int[tid] = 0u;
        __syncthreads();
        int n0 = ((bid - 1) * 4 + w) * RPW;
#pragma unroll
        for (int r = 0; r < RPW; ++r) { blo[r] = 0u; bhi[r] = 0u; }
#pragma unroll
        for (int r = 0; r < RPW; ++r) {
            int n = n0 + r;
            if (n < N_NODES) {
                const float4* hrow = (const float4*)(H + (size_t)n * NUM_EDGE);
                float4* orow = (float4*)(out + (size_t)n * EOUT + KF);
                float4 v[16];
#pragma unroll
                for (int c = 0; c < 16; ++c) v[c] = hrow[c * 64 + lane];
                unsigned lo = 0u, hi = 0u;
#pragma unroll
                for (int c = 0; c < 16; ++c) {
                    orow[c * 64 + lane] = v[c];
                    unsigned bx = (__float_as_uint(v[c].x) != 0u) ? 1u : 0u;  // H in {0,1}
                    unsigned by = (__float_as_uint(v[c].y) != 0u) ? 1u : 0u;
                    unsigned bz = (__float_as_uint(v[c].z) != 0u) ? 1u : 0u;
                    unsigned bw = (__float_as_uint(v[c].w) != 0u) ? 1u : 0u;
                    int b = (c & 7) * 4;
                    unsigned bits = (bx << b) | (by << (b + 1)) | (bz << (b + 2)) | (bw << (b + 3));
                    if (c < 8) lo |= bits; else hi |= bits;
                }
                blo[r] = lo; bhi[r] = hi;
            }
        }
#pragma unroll
        for (int r = 0; r < RPW; ++r) rs[r] = (unsigned)(__popc(blo[r]) + __popc(bhi[r]));
#pragma unroll
        for (int st = 32; st > 0; st >>= 1) {
#pragma unroll
            for (int r = 0; r < RPW; ++r) rs[r] += __shfl_xor(rs[r], st);
        }
    }

    grid.sync();   // masks published; streamer registers persist

    if (bid != 0) {
        // ---- Stage 3: mask-dependent Phase B (validated round-10 logic) ----
        int n0 = ((bid - 1) * 4 + w) * RPW;
        unsigned packed[RPW];
#pragma unroll
        for (int r = 0; r < RPW; ++r) {
            packed[r] = 0u;
            int n = n0 + r;
            if (n < N_NODES) {
                unsigned m = mask32[n];
                unsigned degraw = rs[r] + 2u * (unsigned)__popc(m & 255u);
                packed[r] = degraw + (1u << 24);
                if (lane < KF) {
                    unsigned sel = (m >> lane) & 1u;
                    out[(size_t)n * EOUT + lane] = sel ? 2.0f : 0.0f;
                    if (sel) atomicAdd(&s_int[lane], packed[r]);
                }
                if (lane == 0)
                    out[(size_t)N_NODES * EOUT + n] =
                        (degraw > 0u) ? (float)(1.0 / sqrt((double)degraw)) : 1.0f;
            }
        }
        // bits -> per-column packed (sum:24|cnt:8) into LDS (conflict-free layout)
#pragma unroll
        for (int cj = 0; cj < 64; ++cj) {
            unsigned val = 0u;
#pragma unroll
            for (int r = 0; r < RPW; ++r) {
                unsigned bits = (cj < 32) ? blo[r] : bhi[r];
                if ((bits >> (cj & 31)) & 1u) val += packed[r];
            }
            if (val) atomicAdd(&lacc[cj * 64 + lane], val);
        }
        __syncthreads();
        // LDS -> global packed u64 atomics (one per column per block)
        for (int i = tid; i < NUM_EDGE; i += 256) {
            unsigned p = lacc[i];
            int lane_i = i & 63, cj = i >> 6, c = cj >> 2, j = cj & 3;
            int col = (c * 64 + lane_i) * 4 + j;
            if (p) atomicAdd(&accum64[KF + col],
                             (unsigned long long)(p & 0xFFFFFFu) |
                             ((unsigned long long)(p >> 24) << 32));
        }
        if (tid < KF) {
            unsigned p = s_int[tid];
            if (p) atomicAdd(&accum64[tid],
                             (unsigned long long)(p & 0xFFFFFFu) |
                             ((unsigned long long)(p >> 24) << 32));
        }
    }

    grid.sync();   // accum64 complete

    if (bid == 0) {
        // ---- Stage 4: degE ----
        for (int j = tid; j < EOUT; j += 256) {
            unsigned long long a = accum64[j];
            unsigned su = (unsigned)a, c = (unsigned)(a >> 32);
            double mean = (double)su / (double)(c ? c : 1u);
            out[(size_t)N_NODES * EOUT + N_NODES + j] = (float)(1.0 / sqrt(mean));
        }
    }
}

extern "C" void kernel_launch(void* const* d_in, const int* in_sizes, int n_in,
                              void* d_out, int out_size, void* d_ws, size_t ws_size,
                              hipStream_t stream) {
    const float* hidden  = (const float*)d_in[0];
    const float* H       = (const float*)d_in[1];
    const float* int_emb = (const float*)d_in[2];
    float* out = (float*)d_out;
    char* ws = (char*)d_ws;

    // ws layout (bytes): keys 640000 | mask32 80000 | accum64 32832 (720000 % 8 == 0)
    unsigned*           keys    = (unsigned*)ws;
    unsigned*           mask32  = (unsigned*)(ws + 640000);
    unsigned long long* accum64 = (unsigned long long*)(ws + 720000);

    void* args[] = { (void*)&H, (void*)&hidden, (void*)&int_emb, (void*)&out,
                     (void*)&keys, (void*)&mask32, (void*)&accum64 };
    hipLaunchCooperativeKernel((void*)kFused, dim3(NBLK), dim3(256), args, 0, stream);
}

// Round 14
// 420.278 us; speedup vs baseline: 3.0087x; 3.0087x over previous
//
#include <hip/hip_runtime.h>
#include <math.h>

#define N_NODES 20000
#define NUM_EDGE 4096
#define DIM 256
#define KF 8
#define EOUT (KF + NUM_EDGE)   /* 4104 */
#define SEL 6001               /* floor(0.3*N)=6000 -> rank<=6000 -> 6001 nodes selected */

__device__ __forceinline__ unsigned fkey(float s) {
    unsigned u = __float_as_uint(s);
    return (u & 0x80000000u) ? ~u : (u | 0x80000000u);
}

__device__ __forceinline__ double wred(double v) {
#pragma unroll
    for (int m = 32; m > 0; m >>= 1) v += __shfl_xor(v, m);
    return v;
}
__device__ __forceinline__ unsigned wredu(unsigned v) {
#pragma unroll
    for (int m = 32; m > 0; m >>= 1) v += __shfl_xor(v, m);
    return v;
}
__device__ __forceinline__ float wredf(float v) {
#pragma unroll
    for (int m = 32; m > 0; m >>= 1) v += __shfl_xor(v, m);
    return v;
}

// Inline selection-mask helper: lane<8 evaluates factor `lane` for node n.
__device__ __forceinline__ unsigned row_mask(int n, int lane,
                                             const unsigned* __restrict__ keys,
                                             const unsigned* T_s, const int* need_s,
                                             const int* eqn_s, const int* eql_s) {
    bool sel = false;
    if (lane < KF) {
        unsigned key = keys[(size_t)lane * N_NODES + n];
        unsigned t = T_s[lane];
        sel = key > t;
        if (key == t) {
            int ne = eqn_s[lane], nd = need_s[lane], pos = -1;
            for (int i = 0; i < ne; ++i) if (eql_s[lane * 64 + i] == n) { pos = i; break; }
            sel = (pos >= 0 && pos < nd);
        }
    }
    return (unsigned)(__ballot(sel) & 0xFFull);
}

// K1e: en (per-block, bit-identical to k0) + keys. Block 0 also zeroes accum64.
__global__ __launch_bounds__(256) void k1e(const float* __restrict__ hidden,
                                           const float* __restrict__ int_emb,
                                           unsigned* __restrict__ keys,
                                           unsigned* __restrict__ accum32) {
    __shared__ float en_s[KF * DIM];
    int tid = threadIdx.x, lane = tid & 63, w = tid >> 6;
    if (blockIdx.x == 0) {
        for (int i = tid; i < 2 * EOUT; i += 256) accum32[i] = 0u;
    }
    for (int f = w; f < KF; f += 4) {
        float4 e = ((const float4*)(int_emb + f * DIM))[lane];
        double ss = (double)e.x * e.x + (double)e.y * e.y + (double)e.z * e.z + (double)e.w * e.w;
        ss = wred(ss);
        float den = fmaxf((float)sqrt(ss), 1e-8f);
        float4 o;
        o.x = e.x / den; o.y = e.y / den; o.z = e.z / den; o.w = e.w / den;
        ((float4*)(en_s + f * DIM))[lane] = o;
    }
    __syncthreads();
    int n = blockIdx.x * 4 + w;
    if (n >= N_NODES) return;
    float4 h = ((const float4*)(hidden + (size_t)n * DIM))[lane];
    double ss = (double)h.x * h.x + (double)h.y * h.y + (double)h.z * h.z + (double)h.w * h.w;
    ss = wred(ss);
    float den = fmaxf((float)sqrt(ss), 1e-8f);
    float hn0 = h.x / den, hn1 = h.y / den, hn2 = h.z / den, hn3 = h.w / den;
    double mydot = 0.0;
#pragma unroll
    for (int f = 0; f < KF; ++f) {
        float4 e = ((const float4*)(en_s + f * DIM))[lane];
        double d = (double)hn0 * e.x + (double)hn1 * e.y + (double)hn2 * e.z + (double)hn3 * e.w;
        d = wred(d);
        if (lane == f) mydot = d;
    }
    if (lane < KF)
        keys[(size_t)lane * N_NODES + n] = fkey((float)(10.0 * mydot));
}

// K2: per factor: radix-select threshold key T, #ties needed, sorted tie list. (validated)
__global__ __launch_bounds__(1024) void k2_select(const unsigned* __restrict__ keys,
                                                  unsigned* __restrict__ T, int* __restrict__ need,
                                                  int* __restrict__ eqn, int* __restrict__ eqlist) {
    int f = blockIdx.x, tid = threadIdx.x;
    const unsigned* col = keys + (size_t)f * N_NODES;
    __shared__ unsigned hist[256];
    __shared__ int s_neq;
    unsigned prefix = 0u, pmask = 0u;
    int k = SEL;
    for (int shift = 24; shift >= 0; shift -= 8) {
        if (tid < 256) hist[tid] = 0u;
        __syncthreads();
        for (int i = tid; i < N_NODES; i += 1024) {
            unsigned key = col[i];
            if ((key & pmask) == prefix) atomicAdd(&hist[(key >> shift) & 255u], 1u);
        }
        __syncthreads();
        int acc = 0; unsigned chosen = 0u;   // identical scan in every thread
        for (int b = 255; b >= 0; --b) {
            int c = (int)hist[b];
            if (acc + c >= k) { chosen = (unsigned)b; k -= acc; break; }
            acc += c;
        }
        prefix |= chosen << shift;
        pmask |= 255u << shift;
        __syncthreads();
    }
    if (tid == 0) { T[f] = prefix; need[f] = k; s_neq = 0; }
    __syncthreads();
    for (int i = tid; i < N_NODES; i += 1024) {
        if (col[i] == prefix) {
            int p = atomicAdd(&s_neq, 1);
            if (p < 64) eqlist[f * 64 + p] = i;
        }
    }
    __syncthreads();
    if (tid == 0) {
        int ne = s_neq < 64 ? s_neq : 64;
        for (int a = 1; a < ne; ++a) {
            int v = eqlist[f * 64 + a]; int b = a - 1;
            while (b >= 0 && eqlist[f * 64 + b] > v) { eqlist[f * 64 + b + 1] = eqlist[f * 64 + b]; --b; }
            eqlist[f * 64 + b + 1] = v;
        }
        eqn[f] = ne;
    }
}

// kA: lean streaming pass. 5000 blocks x 4 waves, 1 row/wave. Copy + bitpack +
//     rowsum + inline mask + int_H/degV writes + bits/degraw to ws. No column acc.
__global__ __launch_bounds__(256) void kA_bits(const float* __restrict__ H,
                                               const unsigned* __restrict__ keys,
                                               const unsigned* __restrict__ T,
                                               const int* __restrict__ need,
                                               const int* __restrict__ eqn,
                                               const int* __restrict__ eqlist,
                                               float* __restrict__ out,
                                               unsigned* __restrict__ degraw_u,
                                               unsigned long long* __restrict__ bits,
                                               unsigned long long* __restrict__ accum64) {
    __shared__ unsigned T_s[KF];
    __shared__ int need_s[KF], eqn_s[KF], eql_s[KF * 64];
    __shared__ unsigned s_int[KF];
    int tid = threadIdx.x, lane = tid & 63, w = tid >> 6;
    if (tid < KF) { T_s[tid] = T[tid]; need_s[tid] = need[tid]; eqn_s[tid] = eqn[tid]; s_int[tid] = 0u; }
    for (int i = tid; i < KF * 64; i += 256) eql_s[i] = eqlist[i];
    __syncthreads();
    int n = blockIdx.x * 4 + w;
    unsigned m = row_mask(n, lane, keys, T_s, need_s, eqn_s, eql_s);
    const float4* hrow = (const float4*)(H + (size_t)n * NUM_EDGE);
    float4* orow = (float4*)(out + (size_t)n * EOUT + KF);
    float4 v[16];
#pragma unroll
    for (int c = 0; c < 16; ++c) v[c] = hrow[c * 64 + lane];
    unsigned lo = 0u, hi = 0u;
#pragma unroll
    for (int c = 0; c < 16; ++c) {
        orow[c * 64 + lane] = v[c];
        unsigned bx = (__float_as_uint(v[c].x) != 0u) ? 1u : 0u;   // H in {0.0f, 1.0f}
        unsigned by = (__float_as_uint(v[c].y) != 0u) ? 1u : 0u;
        unsigned bz = (__float_as_uint(v[c].z) != 0u) ? 1u : 0u;
        unsigned bw = (__float_as_uint(v[c].w) != 0u) ? 1u : 0u;
        int b = (c & 7) * 4;
        unsigned bb = (bx << b) | (by << (b + 1)) | (bz << (b + 2)) | (bw << (b + 3));
        if (c < 8) lo |= bb; else hi |= bb;
    }
    bits[(size_t)n * 64 + lane] = (unsigned long long)lo | ((unsigned long long)hi << 32);
    unsigned rs = wredu((unsigned)(__popc(lo) + __popc(hi)));
    unsigned degraw = rs + 2u * (unsigned)__popc(m);
    unsigned packed = degraw + (1u << 24);
    if (lane < KF) {
        unsigned sel = (m >> lane) & 1u;
        out[(size_t)n * EOUT + lane] = sel ? 2.0f : 0.0f;
        if (sel) atomicAdd(&s_int[lane], packed);
    }
    if (lane == 0) {
        degraw_u[n] = degraw;
        out[(size_t)N_NODES * EOUT + n] =
            (degraw > 0u) ? (float)(1.0 / sqrt((double)degraw)) : 1.0f;
    }
    __syncthreads();
    if (tid < KF) {
        unsigned p = s_int[tid];
        if (p) atomicAdd(&accum64[tid],
                         (unsigned long long)(p & 0xFFFFFFu) |
                         ((unsigned long long)(p >> 24) << 32));
    }
}

// kB: column stats from the 32x-compressed bits (L2-resident). 500 blocks x 4 waves x 10 rows.
//     Validated expansion + LDS + packed u64 atomics.
__global__ __launch_bounds__(256) void kB_bits(const unsigned long long* __restrict__ bits,
                                               const unsigned* __restrict__ degraw_u,
                                               unsigned long long* __restrict__ accum64) {
    __shared__ unsigned lacc[NUM_EDGE];
    int tid = threadIdx.x, lane = tid & 63, w = tid >> 6;
    for (int i = tid; i < NUM_EDGE; i += 256) lacc[i] = 0u;
    __syncthreads();
    int n0 = (blockIdx.x * 4 + w) * 10;
    unsigned blo[10], bhi[10], packed[10];
#pragma unroll
    for (int r = 0; r < 10; ++r) {
        unsigned long long b = bits[(size_t)(n0 + r) * 64 + lane];
        blo[r] = (unsigned)b; bhi[r] = (unsigned)(b >> 32);
        packed[r] = degraw_u[n0 + r] + (1u << 24);
    }
#pragma unroll
    for (int cj = 0; cj < 64; ++cj) {
        unsigned val = 0u;
#pragma unroll
        for (int r = 0; r < 10; ++r) {
            unsigned bb = (cj < 32) ? blo[r] : bhi[r];
            if ((bb >> (cj & 31)) & 1u) val += packed[r];
        }
        if (val) atomicAdd(&lacc[cj * 64 + lane], val);
    }
    __syncthreads();
    for (int i = tid; i < NUM_EDGE; i += 256) {
        unsigned p = lacc[i];
        int lane_i = i & 63, cj = i >> 6, c = cj >> 2, j = cj & 3;
        int col = (c * 64 + lane_i) * 4 + j;
        if (p) atomicAdd(&accum64[KF + col],
                         (unsigned long long)(p & 0xFFFFFFu) |
                         ((unsigned long long)(p >> 24) << 32));
    }
}

// kABm: fallback (small ws) — round-11 kAB with inline mask. 500 blocks x 4 waves x 10 rows.
__global__ __launch_bounds__(256) void kABm(const float* __restrict__ H,
                                            const unsigned* __restrict__ keys,
                                            const unsigned* __restrict__ T,
                                            const int* __restrict__ need,
                                            const int* __restrict__ eqn,
                                            const int* __restrict__ eqlist,
                                            float* __restrict__ out,
                                            unsigned long long* __restrict__ accum64) {
    __shared__ unsigned lacc[NUM_EDGE];
    __shared__ unsigned s_int[KF];
    __shared__ unsigned T_s[KF];
    __shared__ int need_s[KF], eqn_s[KF], eql_s[KF * 64];
    int tid = threadIdx.x, lane = tid & 63, w = tid >> 6;
    for (int i = tid; i < NUM_EDGE; i += 256) lacc[i] = 0u;
    if (tid < KF) { T_s[tid] = T[tid]; need_s[tid] = need[tid]; eqn_s[tid] = eqn[tid]; s_int[tid] = 0u; }
    for (int i = tid; i < KF * 64; i += 256) eql_s[i] = eqlist[i];
    __syncthreads();
    unsigned acc[64];
#pragma unroll
    for (int i = 0; i < 64; ++i) acc[i] = 0u;
    int n0 = (blockIdx.x * 4 + w) * 10;
    for (int r = 0; r < 10; ++r) {
        int n = n0 + r;
        const float4* hrow = (const float4*)(H + (size_t)n * NUM_EDGE);
        float4* orow = (float4*)(out + (size_t)n * EOUT + KF);
        float4 v[16];
#pragma unroll
        for (int c = 0; c < 16; ++c) v[c] = hrow[c * 64 + lane];
        float rsum = 0.f;
#pragma unroll
        for (int c = 0; c < 16; ++c) {
            orow[c * 64 + lane] = v[c];
            rsum += (v[c].x + v[c].y) + (v[c].z + v[c].w);
        }
        rsum = wredf(rsum);
        unsigned m = row_mask(n, lane, keys, T_s, need_s, eqn_s, eql_s);
        float degraw = rsum + 2.f * (float)__popc(m);
        unsigned packed = (unsigned)degraw + (1u << 24);
        if (lane < KF) {
            unsigned sel = (m >> lane) & 1u;
            out[(size_t)n * EOUT + lane] = sel ? 2.0f : 0.0f;
            if (sel) atomicAdd(&s_int[lane], packed);
        }
        if (lane == 0)
            out[(size_t)N_NODES * EOUT + n] =
                (degraw > 0.f) ? (float)(1.0 / sqrt((double)degraw)) : 1.0f;
#pragma unroll
        for (int c = 0; c < 16; ++c) {
            if (v[c].x != 0.f) acc[c * 4 + 0] += packed;
            if (v[c].y != 0.f) acc[c * 4 + 1] += packed;
            if (v[c].z != 0.f) acc[c * 4 + 2] += packed;
            if (v[c].w != 0.f) acc[c * 4 + 3] += packed;
        }
    }
#pragma unroll
    for (int cj = 0; cj < 64; ++cj)
        atomicAdd(&lacc[cj * 64 + lane], acc[cj]);
    __syncthreads();
    for (int i = tid; i < NUM_EDGE; i += 256) {
        unsigned p = lacc[i];
        int lane_i = i & 63, cj = i >> 6, c = cj >> 2, j = cj & 3;
        int col = (c * 64 + lane_i) * 4 + j;
        if (p) atomicAdd(&accum64[KF + col],
                         (unsigned long long)(p & 0xFFFFFFu) |
                         ((unsigned long long)(p >> 24) << 32));
    }
    if (tid < KF) {
        unsigned p = s_int[tid];
        if (p) atomicAdd(&accum64[tid],
                         (unsigned long long)(p & 0xFFFFFFu) |
                         ((unsigned long long)(p >> 24) << 32));
    }
}

// K4: degE[j] = (sum/max(cnt,1))^-0.5 from packed u64.
__global__ __launch_bounds__(256) void k4_dege(const unsigned long long* __restrict__ accum64,
                                               float* __restrict__ out) {
    int j = blockIdx.x * 256 + threadIdx.x;
    if (j >= EOUT) return;
    unsigned long long a = accum64[j];
    unsigned s = (unsigned)a, c = (unsigned)(a >> 32);
    double mean = (double)s / (double)(c ? c : 1u);
    out[(size_t)N_NODES * EOUT + N_NODES + j] = (float)(1.0 / sqrt(mean));
}

extern "C" void kernel_launch(void* const* d_in, const int* in_sizes, int n_in,
                              void* d_out, int out_size, void* d_ws, size_t ws_size,
                              hipStream_t stream) {
    const float* hidden  = (const float*)d_in[0];
    const float* H       = (const float*)d_in[1];
    const float* int_emb = (const float*)d_in[2];
    float* out = (float*)d_out;
    char* ws = (char*)d_ws;

    // ws layout (bytes):
    //   keys    0      .. 640000
    //   T       640000 (32) | need 640032 (32) | eqn 640064 (32) | eqlist 640096 (2048)
    //   accum64 642144 (32832, 8-aligned)
    //   degraw  674976 (80000)
    //   bits    754976 (10,240,000, 8-aligned)   [big-ws path only]
    unsigned*           keys    = (unsigned*)ws;
    unsigned*           T       = (unsigned*)(ws + 640000);
    int*                need    = (int*)(ws + 640032);
    int*                eqn     = (int*)(ws + 640064);
    int*                eqlist  = (int*)(ws + 640096);
    unsigned long long* accum64 = (unsigned long long*)(ws + 642144);
    unsigned*           degraw  = (unsigned*)(ws + 674976);
    unsigned long long* bits    = (unsigned long long*)(ws + 754976);
    bool big = ws_size >= (size_t)754976 + 10240000ull;

    hipLaunchKernelGGL(k1e,       dim3(5000), dim3(256),  0, stream, hidden, int_emb, keys,
                       (unsigned*)accum64);
    hipLaunchKernelGGL(k2_select, dim3(8),    dim3(1024), 0, stream, keys, T, need, eqn, eqlist);
    if (big) {
        hipLaunchKernelGGL(kA_bits, dim3(5000), dim3(256), 0, stream, H, keys, T, need, eqn, eqlist,
                           out, degraw, bits, accum64);
        hipLaunchKernelGGL(kB_bits, dim3(500),  dim3(256), 0, stream, bits, degraw, accum64);
    } else {
        hipLaunchKernelGGL(kABm,    dim3(500),  dim3(256), 0, stream, H, keys, T, need, eqn, eqlist,
                           out, accum64);
    }
    hipLaunchKernelGGL(k4_dege,   dim3(17),   dim3(256),  0, stream, accum64, out);
}

// Round 15
// 266.421 us; speedup vs baseline: 4.7462x; 1.5775x over previous
//
#include <hip/hip_runtime.h>
#include <math.h>

#define N_NODES 20000
#define NUM_EDGE 4096
#define DIM 256
#define KF 8
#define EOUT (KF + NUM_EDGE)   /* 4104 */
#define SEL 6001               /* floor(0.3*N)=6000 -> rank<=6000 -> 6001 nodes selected */

__device__ __forceinline__ unsigned fkey(float s) {
    unsigned u = __float_as_uint(s);
    return (u & 0x80000000u) ? ~u : (u | 0x80000000u);
}

__device__ __forceinline__ double wred(double v) {
#pragma unroll
    for (int m = 32; m > 0; m >>= 1) v += __shfl_xor(v, m);
    return v;
}
__device__ __forceinline__ float wredf(float v) {
#pragma unroll
    for (int m = 32; m > 0; m >>= 1) v += __shfl_xor(v, m);
    return v;
}

// Inline selection-mask helper: lane<8 evaluates factor `lane` for node n.
__device__ __forceinline__ unsigned row_mask(int n, int lane,
                                             const unsigned* __restrict__ keys,
                                             const unsigned* T_s, const int* need_s,
                                             const int* eqn_s, const int* eql_s) {
    bool sel = false;
    if (lane < KF) {
        unsigned key = keys[(size_t)lane * N_NODES + n];
        unsigned t = T_s[lane];
        sel = key > t;
        if (key == t) {
            int ne = eqn_s[lane], nd = need_s[lane], pos = -1;
            for (int i = 0; i < ne; ++i) if (eql_s[lane * 64 + i] == n) { pos = i; break; }
            sel = (pos >= 0 && pos < nd);
        }
    }
    return (unsigned)(__ballot(sel) & 0xFFull);
}

// K1e: en (per-block in LDS, bit-identical to old k0) + keys. Block 0 zeroes accum64.
__global__ __launch_bounds__(256) void k1e(const float* __restrict__ hidden,
                                           const float* __restrict__ int_emb,
                                           unsigned* __restrict__ keys,
                                           unsigned* __restrict__ accum32) {
    __shared__ float en_s[KF * DIM];
    int tid = threadIdx.x, lane = tid & 63, w = tid >> 6;
    if (blockIdx.x == 0) {
        for (int i = tid; i < 2 * EOUT; i += 256) accum32[i] = 0u;
    }
    for (int f = w; f < KF; f += 4) {
        float4 e = ((const float4*)(int_emb + f * DIM))[lane];
        double ss = (double)e.x * e.x + (double)e.y * e.y + (double)e.z * e.z + (double)e.w * e.w;
        ss = wred(ss);
        float den = fmaxf((float)sqrt(ss), 1e-8f);
        float4 o;
        o.x = e.x / den; o.y = e.y / den; o.z = e.z / den; o.w = e.w / den;
        ((float4*)(en_s + f * DIM))[lane] = o;
    }
    __syncthreads();
    int n = blockIdx.x * 4 + w;
    if (n >= N_NODES) return;
    float4 h = ((const float4*)(hidden + (size_t)n * DIM))[lane];
    double ss = (double)h.x * h.x + (double)h.y * h.y + (double)h.z * h.z + (double)h.w * h.w;
    ss = wred(ss);
    float den = fmaxf((float)sqrt(ss), 1e-8f);
    float hn0 = h.x / den, hn1 = h.y / den, hn2 = h.z / den, hn3 = h.w / den;
    double mydot = 0.0;
#pragma unroll
    for (int f = 0; f < KF; ++f) {
        float4 e = ((const float4*)(en_s + f * DIM))[lane];
        double d = (double)hn0 * e.x + (double)hn1 * e.y + (double)hn2 * e.z + (double)hn3 * e.w;
        d = wred(d);
        if (lane == f) mydot = d;
    }
    if (lane < KF)
        keys[(size_t)lane * N_NODES + n] = fkey((float)(10.0 * mydot));
}

// K2: per factor: radix-select threshold key T, #ties needed, sorted tie list. (validated)
__global__ __launch_bounds__(1024) void k2_select(const unsigned* __restrict__ keys,
                                                  unsigned* __restrict__ T, int* __restrict__ need,
                                                  int* __restrict__ eqn, int* __restrict__ eqlist) {
    int f = blockIdx.x, tid = threadIdx.x;
    const unsigned* col = keys + (size_t)f * N_NODES;
    __shared__ unsigned hist[256];
    __shared__ int s_neq;
    unsigned prefix = 0u, pmask = 0u;
    int k = SEL;
    for (int shift = 24; shift >= 0; shift -= 8) {
        if (tid < 256) hist[tid] = 0u;
        __syncthreads();
        for (int i = tid; i < N_NODES; i += 1024) {
            unsigned key = col[i];
            if ((key & pmask) == prefix) atomicAdd(&hist[(key >> shift) & 255u], 1u);
        }
        __syncthreads();
        int acc = 0; unsigned chosen = 0u;   // identical scan in every thread
        for (int b = 255; b >= 0; --b) {
            int c = (int)hist[b];
            if (acc + c >= k) { chosen = (unsigned)b; k -= acc; break; }
            acc += c;
        }
        prefix |= chosen << shift;
        pmask |= 255u << shift;
        __syncthreads();
    }
    if (tid == 0) { T[f] = prefix; need[f] = k; s_neq = 0; }
    __syncthreads();
    for (int i = tid; i < N_NODES; i += 1024) {
        if (col[i] == prefix) {
            int p = atomicAdd(&s_neq, 1);
            if (p < 64) eqlist[f * 64 + p] = i;
        }
    }
    __syncthreads();
    if (tid == 0) {
        int ne = s_neq < 64 ? s_neq : 64;
        for (int a = 1; a < ne; ++a) {
            int v = eqlist[f * 64 + a]; int b = a - 1;
            while (b >= 0 && eqlist[f * 64 + b] > v) { eqlist[f * 64 + b + 1] = eqlist[f * 64 + b]; --b; }
            eqlist[f * 64 + b + 1] = v;
        }
        eqn[f] = ne;
    }
}

// kABm: the round-11-validated fused stream (193 us, VGPR~108 forced by acc[64])
//       + inline row_mask (replaces k25/mask32). 500 blocks x 4 waves x 10 rows.
__global__ __launch_bounds__(256) void kABm(const float* __restrict__ H,
                                            const unsigned* __restrict__ keys,
                                            const unsigned* __restrict__ T,
                                            const int* __restrict__ need,
                                            const int* __restrict__ eqn,
                                            const int* __restrict__ eqlist,
                                            float* __restrict__ out,
                                            unsigned long long* __restrict__ accum64) {
    __shared__ unsigned lacc[NUM_EDGE];
    __shared__ unsigned s_int[KF];
    __shared__ unsigned T_s[KF];
    __shared__ int need_s[KF], eqn_s[KF], eql_s[KF * 64];
    int tid = threadIdx.x, lane = tid & 63, w = tid >> 6;
    for (int i = tid; i < NUM_EDGE; i += 256) lacc[i] = 0u;
    if (tid < KF) { T_s[tid] = T[tid]; need_s[tid] = need[tid]; eqn_s[tid] = eqn[tid]; s_int[tid] = 0u; }
    for (int i = tid; i < KF * 64; i += 256) eql_s[i] = eqlist[i];
    __syncthreads();
    unsigned acc[64];
#pragma unroll
    for (int i = 0; i < 64; ++i) acc[i] = 0u;
    int n0 = (blockIdx.x * 4 + w) * 10;
    for (int r = 0; r < 10; ++r) {
        int n = n0 + r;
        const float4* hrow = (const float4*)(H + (size_t)n * NUM_EDGE);
        float4* orow = (float4*)(out + (size_t)n * EOUT + KF);
        float4 v[16];
#pragma unroll
        for (int c = 0; c < 16; ++c) v[c] = hrow[c * 64 + lane];
        float rsum = 0.f;
#pragma unroll
        for (int c = 0; c < 16; ++c) {
            orow[c * 64 + lane] = v[c];
            rsum += (v[c].x + v[c].y) + (v[c].z + v[c].w);
        }
        rsum = wredf(rsum);
        unsigned m = row_mask(n, lane, keys, T_s, need_s, eqn_s, eql_s);
        float degraw = rsum + 2.f * (float)__popc(m);
        unsigned packed = (unsigned)degraw + (1u << 24);
        if (lane < KF) {
            unsigned sel = (m >> lane) & 1u;
            out[(size_t)n * EOUT + lane] = sel ? 2.0f : 0.0f;
            if (sel) atomicAdd(&s_int[lane], packed);
        }
        if (lane == 0)
            out[(size_t)N_NODES * EOUT + n] =
                (degraw > 0.f) ? (float)(1.0 / sqrt((double)degraw)) : 1.0f;
#pragma unroll
        for (int c = 0; c < 16; ++c) {
            if (v[c].x != 0.f) acc[c * 4 + 0] += packed;
            if (v[c].y != 0.f) acc[c * 4 + 1] += packed;
            if (v[c].z != 0.f) acc[c * 4 + 2] += packed;
            if (v[c].w != 0.f) acc[c * 4 + 3] += packed;
        }
    }
    // wave -> LDS. lacc[cj*64 + lane] holds column (c*64+lane)*4+j (cj=c*4+j):
    // consecutive lanes -> consecutive banks (2 lanes/bank = free).
#pragma unroll
    for (int cj = 0; cj < 64; ++cj)
        atomicAdd(&lacc[cj * 64 + lane], acc[cj]);
    __syncthreads();
    // LDS -> global packed u64 atomics (one per column per block).
    for (int i = tid; i < NUM_EDGE; i += 256) {
        unsigned p = lacc[i];
        int lane_i = i & 63, cj = i >> 6, c = cj >> 2, j = cj & 3;
        int col = (c * 64 + lane_i) * 4 + j;
        if (p) atomicAdd(&accum64[KF + col],
                         (unsigned long long)(p & 0xFFFFFFu) |
                         ((unsigned long long)(p >> 24) << 32));
    }
    if (tid < KF) {
        unsigned p = s_int[tid];
        if (p) atomicAdd(&accum64[tid],
                         (unsigned long long)(p & 0xFFFFFFu) |
                         ((unsigned long long)(p >> 24) << 32));
    }
}

// K4: degE[j] = (sum/max(cnt,1))^-0.5 from packed u64.
__global__ __launch_bounds__(256) void k4_dege(const unsigned long long* __restrict__ accum64,
                                               float* __restrict__ out) {
    int j = blockIdx.x * 256 + threadIdx.x;
    if (j >= EOUT) return;
    unsigned long long a = accum64[j];
    unsigned s = (unsigned)a, c = (unsigned)(a >> 32);
    double mean = (double)s / (double)(c ? c : 1u);
    out[(size_t)N_NODES * EOUT + N_NODES + j] = (float)(1.0 / sqrt(mean));
}

extern "C" void kernel_launch(void* const* d_in, const int* in_sizes, int n_in,
                              void* d_out, int out_size, void* d_ws, size_t ws_size,
                              hipStream_t stream) {
    const float* hidden  = (const float*)d_in[0];
    const float* H       = (const float*)d_in[1];
    const float* int_emb = (const float*)d_in[2];
    float* out = (float*)d_out;
    char* ws = (char*)d_ws;

    // ws layout (bytes): keys 640000 | T 32 | need 32 | eqn 32 | eqlist 2048 |
    //                    accum64 32832 (642144 % 8 == 0)
    unsigned*           keys    = (unsigned*)ws;
    unsigned*           T       = (unsigned*)(ws + 640000);
    int*                need    = (int*)(ws + 640032);
    int*                eqn     = (int*)(ws + 640064);
    int*                eqlist  = (int*)(ws + 640096);
    unsigned long long* accum64 = (unsigned long long*)(ws + 642144);

    hipLaunchKernelGGL(k1e,       dim3(5000), dim3(256),  0, stream, hidden, int_emb, keys,
                       (unsigned*)accum64);
    hipLaunchKernelGGL(k2_select, dim3(8),    dim3(1024), 0, stream, keys, T, need, eqn, eqlist);
    hipLaunchKernelGGL(kABm,      dim3(500),  dim3(256),  0, stream, H, keys, T, need, eqn, eqlist,
                       out, accum64);
    hipLaunchKernelGGL(k4_dege,   dim3(17),   dim3(256),  0, stream, accum64, out);
}

// Round 16
// 254.223 us; speedup vs baseline: 4.9740x; 1.0480x over previous
//
#include <hip/hip_runtime.h>
#include <math.h>

#define N_NODES 20000
#define NUM_EDGE 4096
#define DIM 256
#define KF 8
#define EOUT (KF + NUM_EDGE)   /* 4104 */
#define SEL 6001               /* floor(0.3*N)=6000 -> rank<=6000 -> 6001 nodes selected */
#define NSBLK 500              /* stream blocks */

__device__ __forceinline__ unsigned fkey(float s) {
    unsigned u = __float_as_uint(s);
    return (u & 0x80000000u) ? ~u : (u | 0x80000000u);
}

__device__ __forceinline__ double wred(double v) {
#pragma unroll
    for (int m = 32; m > 0; m >>= 1) v += __shfl_xor(v, m);
    return v;
}
__device__ __forceinline__ float wredf(float v) {
#pragma unroll
    for (int m = 32; m > 0; m >>= 1) v += __shfl_xor(v, m);
    return v;
}

// K1e: en (per-block in LDS, bit-identical tree to old k0) + keys with interleaved
//      butterflies (same per-factor reduction tree as validated -> bit-identical keys,
//      better ILP; this exact d[8] form passed refcheck in round 13).
__global__ __launch_bounds__(256) void k1e(const float* __restrict__ hidden,
                                           const float* __restrict__ int_emb,
                                           unsigned* __restrict__ keys) {
    __shared__ float en_s[KF * DIM];
    int tid = threadIdx.x, lane = tid & 63, w = tid >> 6;
    for (int f = w; f < KF; f += 4) {
        float4 e = ((const float4*)(int_emb + f * DIM))[lane];
        double ss = (double)e.x * e.x + (double)e.y * e.y + (double)e.z * e.z + (double)e.w * e.w;
        ss = wred(ss);
        float den = fmaxf((float)sqrt(ss), 1e-8f);
        float4 o;
        o.x = e.x / den; o.y = e.y / den; o.z = e.z / den; o.w = e.w / den;
        ((float4*)(en_s + f * DIM))[lane] = o;
    }
    __syncthreads();
    int n = blockIdx.x * 4 + w;
    if (n >= N_NODES) return;
    float4 h = ((const float4*)(hidden + (size_t)n * DIM))[lane];
    double ss = (double)h.x * h.x + (double)h.y * h.y + (double)h.z * h.z + (double)h.w * h.w;
    ss = wred(ss);
    float den = fmaxf((float)sqrt(ss), 1e-8f);
    float hn0 = h.x / den, hn1 = h.y / den, hn2 = h.z / den, hn3 = h.w / den;
    double d[KF];
#pragma unroll
    for (int f = 0; f < KF; ++f) {
        float4 e = ((const float4*)(en_s + f * DIM))[lane];
        d[f] = (double)hn0 * e.x + (double)hn1 * e.y + (double)hn2 * e.z + (double)hn3 * e.w;
    }
#pragma unroll
    for (int st = 32; st > 0; st >>= 1) {
#pragma unroll
        for (int f = 0; f < KF; ++f) d[f] += __shfl_xor(d[f], st);
    }
    if (lane < KF)
        keys[(size_t)lane * N_NODES + n] = fkey((float)(10.0 * d[lane]));
}

// K2: per factor: radix-select threshold key T, #ties needed, sorted tie list. (validated)
__global__ __launch_bounds__(1024) void k2_select(const unsigned* __restrict__ keys,
                                                  unsigned* __restrict__ T, int* __restrict__ need,
                                                  int* __restrict__ eqn, int* __restrict__ eqlist) {
    int f = blockIdx.x, tid = threadIdx.x;
    const unsigned* col = keys + (size_t)f * N_NODES;
    __shared__ unsigned hist[256];
    __shared__ int s_neq;
    unsigned prefix = 0u, pmask = 0u;
    int k = SEL;
    for (int shift = 24; shift >= 0; shift -= 8) {
        if (tid < 256) hist[tid] = 0u;
        __syncthreads();
        for (int i = tid; i < N_NODES; i += 1024) {
            unsigned key = col[i];
            if ((key & pmask) == prefix) atomicAdd(&hist[(key >> shift) & 255u], 1u);
        }
        __syncthreads();
        int acc = 0; unsigned chosen = 0u;   // identical scan in every thread
        for (int b = 255; b >= 0; --b) {
            int c = (int)hist[b];
            if (acc + c >= k) { chosen = (unsigned)b; k -= acc; break; }
            acc += c;
        }
        prefix |= chosen << shift;
        pmask |= 255u << shift;
        __syncthreads();
    }
    if (tid == 0) { T[f] = prefix; need[f] = k; s_neq = 0; }
    __syncthreads();
    for (int i = tid; i < N_NODES; i += 1024) {
        if (col[i] == prefix) {
            int p = atomicAdd(&s_neq, 1);
            if (p < 64) eqlist[f * 64 + p] = i;
        }
    }
    __syncthreads();
    if (tid == 0) {
        int ne = s_neq < 64 ? s_neq : 64;
        for (int a = 1; a < ne; ++a) {
            int v = eqlist[f * 64 + a]; int b = a - 1;
            while (b >= 0 && eqlist[f * 64 + b] > v) { eqlist[f * 64 + b + 1] = eqlist[f * 64 + b]; --b; }
            eqlist[f * 64 + b + 1] = v;
        }
        eqn[f] = ne;
    }
}

// K2.5: per-node selection mask; also zero the u64 degE accumulator (as u32 lanes). (validated)
__global__ __launch_bounds__(256) void k25_mask(const unsigned* __restrict__ keys,
                                                const unsigned* __restrict__ T, const int* __restrict__ need,
                                                const int* __restrict__ eqn, const int* __restrict__ eqlist,
                                                unsigned* __restrict__ mask32, unsigned* __restrict__ accum32) {
    int g = blockIdx.x * 256 + threadIdx.x;
    if (g < 2 * EOUT) accum32[g] = 0u;
    if (g >= N_NODES) return;
    unsigned m = 0u;
#pragma unroll
    for (int f = 0; f < KF; ++f) {
        unsigned key = keys[(size_t)f * N_NODES + g];
        unsigned t = T[f];
        bool sel = key > t;
        if (key == t) {
            int ne = eqn[f], nd = need[f], pos = -1;
            for (int i = 0; i < ne; ++i) if (eqlist[f * 64 + i] == g) { pos = i; break; }
            sel = (pos >= 0 && pos < nd);
        }
        m |= (sel ? 1u : 0u) << f;
    }
    mask32[g] = m;
}

// kAB: round-11 fused stream (193 us) with the global-ATOMIC tail replaced by a
//      plain coalesced store of the per-block packed partials (A/B test of the
//      atomic-storm hypothesis). Only the 8 int_H counters remain atomic.
__global__ __launch_bounds__(256) void kAB(const float* __restrict__ H,
                                           const unsigned* __restrict__ mask32,
                                           float* __restrict__ out,
                                           unsigned long long* __restrict__ accum64,
                                           unsigned* __restrict__ partial) {
    __shared__ unsigned lacc[NUM_EDGE];
    __shared__ unsigned s_int[KF];
    int tid = threadIdx.x, lane = tid & 63, w = tid >> 6;
    for (int i = tid; i < NUM_EDGE; i += 256) lacc[i] = 0u;
    if (tid < KF) s_int[tid] = 0u;
    __syncthreads();
    unsigned acc[64];
#pragma unroll
    for (int i = 0; i < 64; ++i) acc[i] = 0u;
    int n0 = (blockIdx.x * 4 + w) * 10;
    for (int r = 0; r < 10; ++r) {
        int n = n0 + r;
        const float4* hrow = (const float4*)(H + (size_t)n * NUM_EDGE);
        float4* orow = (float4*)(out + (size_t)n * EOUT + KF);
        float4 v[16];
#pragma unroll
        for (int c = 0; c < 16; ++c) v[c] = hrow[c * 64 + lane];
        float rsum = 0.f;
#pragma unroll
        for (int c = 0; c < 16; ++c) {
            orow[c * 64 + lane] = v[c];
            rsum += (v[c].x + v[c].y) + (v[c].z + v[c].w);
        }
        rsum = wredf(rsum);
        unsigned m = mask32[n];
        float degraw = rsum + 2.f * (float)__popc(m & 255u);   // exact small integer
        unsigned packed = (unsigned)degraw + (1u << 24);
        if (lane < KF) {
            unsigned sel = (m >> lane) & 1u;
            out[(size_t)n * EOUT + lane] = sel ? 2.0f : 0.0f;
            if (sel) atomicAdd(&s_int[lane], packed);
        }
        if (lane == 0)
            out[(size_t)N_NODES * EOUT + n] =
                (degraw > 0.f) ? (float)(1.0 / sqrt((double)degraw)) : 1.0f;
#pragma unroll
        for (int c = 0; c < 16; ++c) {
            if (v[c].x != 0.f) acc[c * 4 + 0] += packed;
            if (v[c].y != 0.f) acc[c * 4 + 1] += packed;
            if (v[c].z != 0.f) acc[c * 4 + 2] += packed;
            if (v[c].w != 0.f) acc[c * 4 + 3] += packed;
        }
    }
    // wave -> LDS (conflict-free: consecutive lanes -> consecutive banks).
#pragma unroll
    for (int cj = 0; cj < 64; ++cj)
        atomicAdd(&lacc[cj * 64 + lane], acc[cj]);
    __syncthreads();
    // LDS -> per-block partial buffer, plain coalesced stores (NO global atomics).
    for (int i = tid; i < NUM_EDGE; i += 256)
        partial[(size_t)blockIdx.x * NUM_EDGE + i] = lacc[i];
    if (tid < KF) {
        unsigned p = s_int[tid];
        if (p) atomicAdd(&accum64[tid],
                         (unsigned long long)(p & 0xFFFFFFu) |
                         ((unsigned long long)(p >> 24) << 32));
    }
}

// kR: reduce 500 per-block partials -> accum64[KF + col] (non-atomic; coalesced reads).
//     lacc index i maps to column col = (c*64+lane)*4+j where i = (c*4+j)*64+lane.
__global__ __launch_bounds__(256) void kR_reduce(const unsigned* __restrict__ partial,
                                                 unsigned long long* __restrict__ accum64) {
    int i = blockIdx.x * 256 + threadIdx.x;   // 16 blocks x 256 = 4096
    unsigned lo = 0u, hi = 0u;
    for (int b = 0; b < NSBLK; ++b) {
        unsigned p = partial[(size_t)b * NUM_EDGE + i];
        lo += p & 0xFFFFFFu;
        hi += p >> 24;
    }
    int lane_i = i & 63, cj = i >> 6, c = cj >> 2, j = cj & 3;
    int col = (c * 64 + lane_i) * 4 + j;
    accum64[KF + col] = (unsigned long long)lo | ((unsigned long long)hi << 32);
}

// K4: degE[j] = (sum/max(cnt,1))^-0.5 from packed u64.
__global__ __launch_bounds__(256) void k4_dege(const unsigned long long* __restrict__ accum64,
                                               float* __restrict__ out) {
    int j = blockIdx.x * 256 + threadIdx.x;
    if (j >= EOUT) return;
    unsigned long long a = accum64[j];
    unsigned s = (unsigned)a, c = (unsigned)(a >> 32);
    double mean = (double)s / (double)(c ? c : 1u);
    out[(size_t)N_NODES * EOUT + N_NODES + j] = (float)(1.0 / sqrt(mean));
}

extern "C" void kernel_launch(void* const* d_in, const int* in_sizes, int n_in,
                              void* d_out, int out_size, void* d_ws, size_t ws_size,
                              hipStream_t stream) {
    const float* hidden  = (const float*)d_in[0];
    const float* H       = (const float*)d_in[1];
    const float* int_emb = (const float*)d_in[2];
    float* out = (float*)d_out;
    char* ws = (char*)d_ws;

    // ws layout (bytes):
    //   keys    0      (640000)
    //   T       640000 (32) | need 640032 (32) | eqn 640064 (32) | eqlist 640096 (2048)
    //   accum64 642144 (32832, 8-aligned)
    //   mask32  674976 (80000)
    //   partial 754976 (8,192,000)  -- region proven present in round 14
    unsigned*           keys    = (unsigned*)ws;
    unsigned*           T       = (unsigned*)(ws + 640000);
    int*                need    = (int*)(ws + 640032);
    int*                eqn     = (int*)(ws + 640064);
    int*                eqlist  = (int*)(ws + 640096);
    unsigned long long* accum64 = (unsigned long long*)(ws + 642144);
    unsigned*           mask32  = (unsigned*)(ws + 674976);
    unsigned*           partial = (unsigned*)(ws + 754976);

    hipLaunchKernelGGL(k1e,       dim3(5000), dim3(256),  0, stream, hidden, int_emb, keys);
    hipLaunchKernelGGL(k2_select, dim3(8),    dim3(1024), 0, stream, keys, T, need, eqn, eqlist);
    hipLaunchKernelGGL(k25_mask,  dim3(80),   dim3(256),  0, stream, keys, T, need, eqn, eqlist,
                       mask32, (unsigned*)accum64);
    hipLaunchKernelGGL(kAB,       dim3(NSBLK), dim3(256), 0, stream, H, mask32, out, accum64, partial);
    hipLaunchKernelGGL(kR_reduce, dim3(16),   dim3(256),  0, stream, partial, accum64);
    hipLaunchKernelGGL(k4_dege,   dim3(17),   dim3(256),  0, stream, accum64, out);
}

// Round 17
// 254.216 us; speedup vs baseline: 4.9741x; 1.0000x over previous
//
#include <hip/hip_runtime.h>
#include <math.h>

#define N_NODES 20000
#define NUM_EDGE 4096
#define DIM 256
#define KF 8
#define EOUT (KF + NUM_EDGE)   /* 4104 */
#define SEL 6001               /* floor(0.3*N)=6000 -> rank<=6000 -> 6001 nodes selected */
#define NSBLK 500              /* stream blocks */

__device__ __forceinline__ unsigned fkey(float s) {
    unsigned u = __float_as_uint(s);
    return (u & 0x80000000u) ? ~u : (u | 0x80000000u);
}

__device__ __forceinline__ double wred(double v) {
#pragma unroll
    for (int m = 32; m > 0; m >>= 1) v += __shfl_xor(v, m);
    return v;
}
__device__ __forceinline__ float wredf(float v) {
#pragma unroll
    for (int m = 32; m > 0; m >>= 1) v += __shfl_xor(v, m);
    return v;
}

// K1e: en (per-block in LDS, bit-identical tree to old k0) + keys with interleaved
//      butterflies (same per-factor reduction tree as validated -> bit-identical keys,
//      better ILP; this exact d[8] form passed refcheck in round 13).
__global__ __launch_bounds__(256) void k1e(const float* __restrict__ hidden,
                                           const float* __restrict__ int_emb,
                                           unsigned* __restrict__ keys) {
    __shared__ float en_s[KF * DIM];
    int tid = threadIdx.x, lane = tid & 63, w = tid >> 6;
    for (int f = w; f < KF; f += 4) {
        float4 e = ((const float4*)(int_emb + f * DIM))[lane];
        double ss = (double)e.x * e.x + (double)e.y * e.y + (double)e.z * e.z + (double)e.w * e.w;
        ss = wred(ss);
        float den = fmaxf((float)sqrt(ss), 1e-8f);
        float4 o;
        o.x = e.x / den; o.y = e.y / den; o.z = e.z / den; o.w = e.w / den;
        ((float4*)(en_s + f * DIM))[lane] = o;
    }
    __syncthreads();
    int n = blockIdx.x * 4 + w;
    if (n >= N_NODES) return;
    float4 h = ((const float4*)(hidden + (size_t)n * DIM))[lane];
    double ss = (double)h.x * h.x + (double)h.y * h.y + (double)h.z * h.z + (double)h.w * h.w;
    ss = wred(ss);
    float den = fmaxf((float)sqrt(ss), 1e-8f);
    float hn0 = h.x / den, hn1 = h.y / den, hn2 = h.z / den, hn3 = h.w / den;
    double d[KF];
#pragma unroll
    for (int f = 0; f < KF; ++f) {
        float4 e = ((const float4*)(en_s + f * DIM))[lane];
        d[f] = (double)hn0 * e.x + (double)hn1 * e.y + (double)hn2 * e.z + (double)hn3 * e.w;
    }
#pragma unroll
    for (int st = 32; st > 0; st >>= 1) {
#pragma unroll
        for (int f = 0; f < KF; ++f) d[f] += __shfl_xor(d[f], st);
    }
    if (lane < KF)
        keys[(size_t)lane * N_NODES + n] = fkey((float)(10.0 * d[lane]));
}

// K2: per factor: radix-select threshold key T, #ties needed, sorted tie list. (validated)
__global__ __launch_bounds__(1024) void k2_select(const unsigned* __restrict__ keys,
                                                  unsigned* __restrict__ T, int* __restrict__ need,
                                                  int* __restrict__ eqn, int* __restrict__ eqlist) {
    int f = blockIdx.x, tid = threadIdx.x;
    const unsigned* col = keys + (size_t)f * N_NODES;
    __shared__ unsigned hist[256];
    __shared__ int s_neq;
    unsigned prefix = 0u, pmask = 0u;
    int k = SEL;
    for (int shift = 24; shift >= 0; shift -= 8) {
        if (tid < 256) hist[tid] = 0u;
        __syncthreads();
        for (int i = tid; i < N_NODES; i += 1024) {
            unsigned key = col[i];
            if ((key & pmask) == prefix) atomicAdd(&hist[(key >> shift) & 255u], 1u);
        }
        __syncthreads();
        int acc = 0; unsigned chosen = 0u;   // identical scan in every thread
        for (int b = 255; b >= 0; --b) {
            int c = (int)hist[b];
            if (acc + c >= k) { chosen = (unsigned)b; k -= acc; break; }
            acc += c;
        }
        prefix |= chosen << shift;
        pmask |= 255u << shift;
        __syncthreads();
    }
    if (tid == 0) { T[f] = prefix; need[f] = k; s_neq = 0; }
    __syncthreads();
    for (int i = tid; i < N_NODES; i += 1024) {
        if (col[i] == prefix) {
            int p = atomicAdd(&s_neq, 1);
            if (p < 64) eqlist[f * 64 + p] = i;
        }
    }
    __syncthreads();
    if (tid == 0) {
        int ne = s_neq < 64 ? s_neq : 64;
        for (int a = 1; a < ne; ++a) {
            int v = eqlist[f * 64 + a]; int b = a - 1;
            while (b >= 0 && eqlist[f * 64 + b] > v) { eqlist[f * 64 + b + 1] = eqlist[f * 64 + b]; --b; }
            eqlist[f * 64 + b + 1] = v;
        }
        eqn[f] = ne;
    }
}

// K2.5: per-node selection mask; also zero the u64 degE accumulator (as u32 lanes). (validated)
__global__ __launch_bounds__(256) void k25_mask(const unsigned* __restrict__ keys,
                                                const unsigned* __restrict__ T, const int* __restrict__ need,
                                                const int* __restrict__ eqn, const int* __restrict__ eqlist,
                                                unsigned* __restrict__ mask32, unsigned* __restrict__ accum32) {
    int g = blockIdx.x * 256 + threadIdx.x;
    if (g < 2 * EOUT) accum32[g] = 0u;
    if (g >= N_NODES) return;
    unsigned m = 0u;
#pragma unroll
    for (int f = 0; f < KF; ++f) {
        unsigned key = keys[(size_t)f * N_NODES + g];
        unsigned t = T[f];
        bool sel = key > t;
        if (key == t) {
            int ne = eqn[f], nd = need[f], pos = -1;
            for (int i = 0; i < ne; ++i) if (eqlist[f * 64 + i] == g) { pos = i; break; }
            sel = (pos >= 0 && pos < nd);
        }
        m |= (sel ? 1u : 0u) << f;
    }
    mask32[g] = m;
}

// kAB: round-11 fused stream (193 us) with the global-ATOMIC tail replaced by a
//      plain coalesced store of the per-block packed partials (A/B test of the
//      atomic-storm hypothesis). Only the 8 int_H counters remain atomic.
__global__ __launch_bounds__(256) void kAB(const float* __restrict__ H,
                                           const unsigned* __restrict__ mask32,
                                           float* __restrict__ out,
                                           unsigned long long* __restrict__ accum64,
                                           unsigned* __restrict__ partial) {
    __shared__ unsigned lacc[NUM_EDGE];
    __shared__ unsigned s_int[KF];
    int tid = threadIdx.x, lane = tid & 63, w = tid >> 6;
    for (int i = tid; i < NUM_EDGE; i += 256) lacc[i] = 0u;
    if (tid < KF) s_int[tid] = 0u;
    __syncthreads();
    unsigned acc[64];
#pragma unroll
    for (int i = 0; i < 64; ++i) acc[i] = 0u;
    int n0 = (blockIdx.x * 4 + w) * 10;
    for (int r = 0; r < 10; ++r) {
        int n = n0 + r;
        const float4* hrow = (const float4*)(H + (size_t)n * NUM_EDGE);
        float4* orow = (float4*)(out + (size_t)n * EOUT + KF);
        float4 v[16];
#pragma unroll
        for (int c = 0; c < 16; ++c) v[c] = hrow[c * 64 + lane];
        float rsum = 0.f;
#pragma unroll
        for (int c = 0; c < 16; ++c) {
            orow[c * 64 + lane] = v[c];
            rsum += (v[c].x + v[c].y) + (v[c].z + v[c].w);
        }
        rsum = wredf(rsum);
        unsigned m = mask32[n];
        float degraw = rsum + 2.f * (float)__popc(m & 255u);   // exact small integer
        unsigned packed = (unsigned)degraw + (1u << 24);
        if (lane < KF) {
            unsigned sel = (m >> lane) & 1u;
            out[(size_t)n * EOUT + lane] = sel ? 2.0f : 0.0f;
            if (sel) atomicAdd(&s_int[lane], packed);
        }
        if (lane == 0)
            out[(size_t)N_NODES * EOUT + n] =
                (degraw > 0.f) ? (float)(1.0 / sqrt((double)degraw)) : 1.0f;
#pragma unroll
        for (int c = 0; c < 16; ++c) {
            if (v[c].x != 0.f) acc[c * 4 + 0] += packed;
            if (v[c].y != 0.f) acc[c * 4 + 1] += packed;
            if (v[c].z != 0.f) acc[c * 4 + 2] += packed;
            if (v[c].w != 0.f) acc[c * 4 + 3] += packed;
        }
    }
    // wave -> LDS (conflict-free: consecutive lanes -> consecutive banks).
#pragma unroll
    for (int cj = 0; cj < 64; ++cj)
        atomicAdd(&lacc[cj * 64 + lane], acc[cj]);
    __syncthreads();
    // LDS -> per-block partial buffer, plain coalesced stores (NO global atomics).
    for (int i = tid; i < NUM_EDGE; i += 256)
        partial[(size_t)blockIdx.x * NUM_EDGE + i] = lacc[i];
    if (tid < KF) {
        unsigned p = s_int[tid];
        if (p) atomicAdd(&accum64[tid],
                         (unsigned long long)(p & 0xFFFFFFu) |
                         ((unsigned long long)(p >> 24) << 32));
    }
}

// kR: reduce 500 per-block partials -> accum64[KF + col] (non-atomic; coalesced reads).
//     lacc index i maps to column col = (c*64+lane)*4+j where i = (c*4+j)*64+lane.
__global__ __launch_bounds__(256) void kR_reduce(const unsigned* __restrict__ partial,
                                                 unsigned long long* __restrict__ accum64) {
    int i = blockIdx.x * 256 + threadIdx.x;   // 16 blocks x 256 = 4096
    unsigned lo = 0u, hi = 0u;
    for (int b = 0; b < NSBLK; ++b) {
        unsigned p = partial[(size_t)b * NUM_EDGE + i];
        lo += p & 0xFFFFFFu;
        hi += p >> 24;
    }
    int lane_i = i & 63, cj = i >> 6, c = cj >> 2, j = cj & 3;
    int col = (c * 64 + lane_i) * 4 + j;
    accum64[KF + col] = (unsigned long long)lo | ((unsigned long long)hi << 32);
}

// K4: degE[j] = (sum/max(cnt,1))^-0.5 from packed u64.
__global__ __launch_bounds__(256) void k4_dege(const unsigned long long* __restrict__ accum64,
                                               float* __restrict__ out) {
    int j = blockIdx.x * 256 + threadIdx.x;
    if (j >= EOUT) return;
    unsigned long long a = accum64[j];
    unsigned s = (unsigned)a, c = (unsigned)(a >> 32);
    double mean = (double)s / (double)(c ? c : 1u);
    out[(size_t)N_NODES * EOUT + N_NODES + j] = (float)(1.0 / sqrt(mean));
}

extern "C" void kernel_launch(void* const* d_in, const int* in_sizes, int n_in,
                              void* d_out, int out_size, void* d_ws, size_t ws_size,
                              hipStream_t stream) {
    const float* hidden  = (const float*)d_in[0];
    const float* H       = (const float*)d_in[1];
    const float* int_emb = (const float*)d_in[2];
    float* out = (float*)d_out;
    char* ws = (char*)d_ws;

    // ws layout (bytes):
    //   keys    0      (640000)
    //   T       640000 (32) | need 640032 (32) | eqn 640064 (32) | eqlist 640096 (2048)
    //   accum64 642144 (32832, 8-aligned)
    //   mask32  674976 (80000)
    //   partial 754976 (8,192,000)  -- region proven present in round 14
    unsigned*           keys    = (unsigned*)ws;
    unsigned*           T       = (unsigned*)(ws + 640000);
    int*                need    = (int*)(ws + 640032);
    int*                eqn     = (int*)(ws + 640064);
    int*                eqlist  = (int*)(ws + 640096);
    unsigned long long* accum64 = (unsigned long long*)(ws + 642144);
    unsigned*           mask32  = (unsigned*)(ws + 674976);
    unsigned*           partial = (unsigned*)(ws + 754976);

    hipLaunchKernelGGL(k1e,       dim3(5000), dim3(256),  0, stream, hidden, int_emb, keys);
    hipLaunchKernelGGL(k2_select, dim3(8),    dim3(1024), 0, stream, keys, T, need, eqn, eqlist);
    hipLaunchKernelGGL(k25_mask,  dim3(80),   dim3(256),  0, stream, keys, T, need, eqn, eqlist,
                       mask32, (unsigned*)accum64);
    hipLaunchKernelGGL(kAB,       dim3(NSBLK), dim3(256), 0, stream, H, mask32, out, accum64, partial);
    hipLaunchKernelGGL(kR_reduce, dim3(16),   dim3(256),  0, stream, partial, accum64);
    hipLaunchKernelGGL(k4_dege,   dim3(17),   dim3(256),  0, stream, accum64, out);
}